// Round 1
// baseline (167.204 us; speedup 1.0000x reference)
//
#include <hip/hip_runtime.h>

namespace {
constexpr int kRows    = 2048;
constexpr int kL0      = 16384;
constexpr int kN1      = 8195;
constexpr int kN2      = 4101;
constexpr int kN3      = 2054;
constexpr int kThreads = 512;

// LDS layout (floats), buffers aliased across phases:
//  d1  [8195]  : written P1, read at final high-IDWT
//  B   [8196]  : a1 -> la1 -> h1
//  d2  [4101]  : written P2, read at high level-2
//  D   [4102]  : a2 -> la2 -> h2
//  a3  [2054]
//  d3  [2054]
constexpr int OFF_D1 = 0;
constexpr int OFF_B  = 8195;
constexpr int OFF_D2 = 16391;
constexpr int OFF_D  = 20492;
constexpr int OFF_A3 = 24594;
constexpr int OFF_D3 = 26648;
constexpr int kLdsFloats = 28702;   // 114808 bytes

// REC_LO[k] = DEC_LO[7-k]  (used for DWT cA taps in k-order AND IDWT low taps)
__device__ constexpr float RL[8] = {
     0.23037781330885523f,  0.7148465705525415f,   0.6308807679295904f,
    -0.02798376941698385f, -0.18703481171888114f,  0.030841381835986965f,
     0.032883011666982945f, -0.010597401785069032f };
// REC_HI[k] = (-1)^k DEC_LO[k]  (used for DWT cD taps in k-order AND IDWT high taps)
__device__ constexpr float RH[8] = {
    -0.010597401785069032f, -0.032883011666982945f, 0.030841381835986965f,
     0.18703481171888114f,  -0.02798376941698385f, -0.6308807679295904f,
     0.7148465705525415f,   -0.23037781330885523f };
} // namespace

// ext0 = symmetric pad of a[N] by 7 on each side; map ext0 index j -> source index
__device__ __forceinline__ int symidx(int j, int N) {
    if (j < 7) return 6 - j;
    int i = j - 7;
    return (i < N) ? i : (2 * N - 1 - i);
}

// DWT from LDS source: cA[n] = sum_k ext0[2n+1+k]*RL[k], cD likewise with RH
__device__ __forceinline__ void dwt_lds(const float* __restrict__ src, int N,
                                        float* __restrict__ cA, float* __restrict__ cD,
                                        int nOut, int tid) {
    for (int n = tid; n < nOut; n += kThreads) {
        const int base = 2 * n + 1;          // ext0 index at k=0
        float sa = 0.f, sd = 0.f;
        if (base >= 7 && base + 7 < 7 + N) { // whole window interior
            const float* p = src + (base - 7);
            #pragma unroll
            for (int k = 0; k < 8; ++k) {
                float v = p[k];
                sa = fmaf(v, RL[k], sa);
                sd = fmaf(v, RH[k], sd);
            }
        } else {
            #pragma unroll
            for (int k = 0; k < 8; ++k) {
                float v = src[symidx(base + k, N)];
                sa = fmaf(v, RL[k], sa);
                sd = fmaf(v, RH[k], sd);
            }
        }
        cA[n] = sa; cD[n] = sd;
    }
}

// IDWT step. out length = 2n-6 (truncation handled by passing n = len(d)).
// y[2i]   = sum_t a[i+t]*RL[6-2t] + d[i+t]*RH[6-2t]
// y[2i+1] = sum_t a[i+t]*RL[7-2t] + d[i+t]*RH[7-2t]
template <bool HAS_A, bool HAS_D, bool TO_GLOBAL>
__device__ __forceinline__ void idwt_step(const float* __restrict__ a,
                                          const float* __restrict__ d,
                                          int n, float* __restrict__ y, int tid) {
    const int pairs = n - 3;
    for (int i = tid; i < pairs; i += kThreads) {
        float s0 = 0.f, s1 = 0.f;
        #pragma unroll
        for (int t = 0; t < 4; ++t) {
            if (HAS_A) {
                float av = a[i + t];
                s0 = fmaf(av, RL[6 - 2 * t], s0);
                s1 = fmaf(av, RL[7 - 2 * t], s1);
            }
            if (HAS_D) {
                float dv = d[i + t];
                s0 = fmaf(dv, RH[6 - 2 * t], s0);
                s1 = fmaf(dv, RH[7 - 2 * t], s1);
            }
        }
        if (TO_GLOBAL) {
            reinterpret_cast<float2*>(y)[i] = make_float2(s0, s1);
        } else {
            y[2 * i]     = s0;
            y[2 * i + 1] = s1;
        }
    }
}

__global__ void __launch_bounds__(kThreads)
wavelet_kernel(const float* __restrict__ x, float* __restrict__ out, int rows) {
    __shared__ float lds[kLdsFloats];
    float* d1 = lds + OFF_D1;
    float* B  = lds + OFF_B;
    float* d2 = lds + OFF_D2;
    float* D  = lds + OFF_D;
    float* a3 = lds + OFF_A3;
    float* d3 = lds + OFF_D3;

    const int row = blockIdx.x;
    if (row >= rows) return;
    const int tid = threadIdx.x;
    const float* __restrict__ xr = x + (size_t)row * kL0;
    float* __restrict__ lowp  = out + (size_t)row * kL0;
    float* __restrict__ highp = out + (size_t)rows * kL0 + (size_t)row * kL0;

    // ---- P1: level-1 DWT, x (global) -> a1 (B), d1 ----
    for (int n = tid; n < kN1; n += kThreads) {
        const int base = 2 * n + 1;
        float sa = 0.f, sd = 0.f;
        if (base >= 7 && base + 7 < 7 + kL0) {
            const float* p = xr + (base - 7);
            #pragma unroll
            for (int k = 0; k < 8; ++k) {
                float v = p[k];
                sa = fmaf(v, RL[k], sa);
                sd = fmaf(v, RH[k], sd);
            }
        } else {
            #pragma unroll
            for (int k = 0; k < 8; ++k) {
                float v = xr[symidx(base + k, kL0)];
                sa = fmaf(v, RL[k], sa);
                sd = fmaf(v, RH[k], sd);
            }
        }
        B[n] = sa; d1[n] = sd;
    }
    __syncthreads();
    // ---- P2: a1 (B) -> a2 (D), d2 ----
    dwt_lds(B, kN1, D, d2, kN2, tid);
    __syncthreads();
    // ---- P3: a2 (D) -> a3, d3 ----
    dwt_lds(D, kN2, a3, d3, kN3, tid);
    __syncthreads();
    // ---- low path: a3 -> la2 (D) [zero details] ----
    idwt_step<true, false, false>(a3, nullptr, kN3, D, tid);
    __syncthreads();
    // la2 (D, 4102 trunc to 4101) -> la1 (B)
    idwt_step<true, false, false>(D, nullptr, kN2, B, tid);
    __syncthreads();
    // la1 (B, trunc to 8195) -> low (global);  high path start: d3 -> h2 (D)
    idwt_step<true, false, true>(B, nullptr, kN1, lowp, tid);
    idwt_step<false, true, false>(nullptr, d3, kN3, D, tid);
    __syncthreads();
    // h2 (D, trunc 4101) + d2 -> h1 (B)
    idwt_step<true, true, false>(D, d2, kN2, B, tid);
    __syncthreads();
    // h1 (B, trunc 8195) + d1 -> high (global)
    idwt_step<true, true, true>(B, d1, kN1, highp, tid);
}

extern "C" void kernel_launch(void* const* d_in, const int* in_sizes, int n_in,
                              void* d_out, int out_size, void* d_ws, size_t ws_size,
                              hipStream_t stream) {
    (void)n_in; (void)d_ws; (void)ws_size; (void)out_size;
    const float* x = (const float*)d_in[0];
    float* out = (float*)d_out;
    const int rows = in_sizes[0] / kL0;   // 2048
    hipLaunchKernelGGL(wavelet_kernel, dim3(rows), dim3(kThreads), 0, stream,
                       x, out, rows);
}

// Round 2
// 112.148 us; speedup vs baseline: 1.4909x; 1.4909x over previous
//
#include <hip/hip_runtime.h>

namespace {
constexpr int kL0      = 16384;
constexpr int kN1      = 8195;
constexpr int kN2      = 4101;
constexpr int kN3      = 2054;
constexpr int kThreads = 512;

// REC_LO[k] = DEC_LO[7-k]  — serves as DWT cA taps (k-order) AND IDWT low taps
__device__ constexpr float RL[8] = {
     0.23037781330885523f,  0.7148465705525415f,   0.6308807679295904f,
    -0.02798376941698385f, -0.18703481171888114f,  0.030841381835986965f,
     0.032883011666982945f, -0.010597401785069032f };
} // namespace

// ext0 = symmetric pad of a[N] by 7 each side then drop first; ext0 index j -> source index
__device__ __forceinline__ int symidx(int j, int N) {
    if (j < 7) return 6 - j;
    int i = j - 7;
    return (i < N) ? i : (2 * N - 1 - i);
}

// cA-only DWT from LDS: cA[n] = sum_k ext0[2n+1+k]*RL[k]
__device__ __forceinline__ void dwt_lo(const float* __restrict__ src, int N,
                                       float* __restrict__ cA, int nOut, int tid) {
    for (int n = tid; n < nOut; n += kThreads) {
        const int base = 2 * n + 1;
        float sa = 0.f;
        if (base >= 7 && base < N) {
            const float* p = src + (base - 7);
            #pragma unroll
            for (int k = 0; k < 8; ++k) sa = fmaf(p[k], RL[k], sa);
        } else {
            #pragma unroll
            for (int k = 0; k < 8; ++k) sa = fmaf(src[symidx(base + k, N)], RL[k], sa);
        }
        cA[n] = sa;
    }
}

// low-only IDWT: y[2i] = sum_t a[i+t]*RL[6-2t], y[2i+1] = sum_t a[i+t]*RL[7-2t]
// n = (possibly truncated) coeff count; out length 2n-6, pairs n-3.
__device__ __forceinline__ void idwt_lo(const float* __restrict__ a, int n,
                                        float* __restrict__ y, int tid) {
    const int pairs = n - 3;
    for (int i = tid; i < pairs; i += kThreads) {
        float a0 = a[i], a1 = a[i + 1], a2 = a[i + 2], a3 = a[i + 3];
        float s0 = fmaf(a0, RL[6], fmaf(a1, RL[4], fmaf(a2, RL[2], a3 * RL[0])));
        float s1 = fmaf(a0, RL[7], fmaf(a1, RL[5], fmaf(a2, RL[3], a3 * RL[1])));
        y[2 * i]     = s0;
        y[2 * i + 1] = s1;
    }
}

__global__ void __launch_bounds__(kThreads, 6)
wavelet_kernel(const float* __restrict__ x, float* __restrict__ out, int rows) {
    // buf1: a1 -> a3 -> la1   buf2: a2 -> la2   (phase-aliased)
    __shared__ float buf1[kN1 + 1];   // 8196
    __shared__ float buf2[kN2 + 1];   // 4102

    const int row = blockIdx.x;
    if (row >= rows) return;
    const int tid = threadIdx.x;
    const float* __restrict__ xr = x + (size_t)row * kL0;
    float* __restrict__ lowp  = out + (size_t)row * kL0;
    float* __restrict__ highp = out + (size_t)rows * kL0 + (size_t)row * kL0;

    // P1: x (global) -> a1 (buf1)
    for (int n = tid; n < kN1; n += kThreads) {
        const int base = 2 * n + 1;
        float sa = 0.f;
        if (base >= 7 && base < kL0) {
            const float* p = xr + (base - 7);
            #pragma unroll
            for (int k = 0; k < 8; ++k) sa = fmaf(p[k], RL[k], sa);
        } else {
            #pragma unroll
            for (int k = 0; k < 8; ++k) sa = fmaf(xr[symidx(base + k, kL0)], RL[k], sa);
        }
        buf1[n] = sa;
    }
    __syncthreads();
    // P2: a1 (buf1) -> a2 (buf2)
    dwt_lo(buf1, kN1, buf2, kN2, tid);
    __syncthreads();
    // P3: a2 (buf2) -> a3 (buf1[0:2054))   [a1 dead]
    dwt_lo(buf2, kN2, buf1, kN3, tid);
    __syncthreads();
    // I1: a3 (buf1) -> la2 (buf2, len 4102)   [a2 dead]
    idwt_lo(buf1, kN3, buf2, tid);
    __syncthreads();
    // I2: la2 (buf2, trunc 4101) -> la1 (buf1, len 8196)   [a3 dead]
    idwt_lo(buf2, kN2, buf1, tid);
    __syncthreads();
    // I3: la1 (buf1, trunc 8195) -> low (global); high = x - low. 2 pairs/thread, float4 IO.
    for (int w = tid; w < kL0 / 4; w += kThreads) {
        const int i = 2 * w;
        float a0 = buf1[i],     a1 = buf1[i + 1], a2 = buf1[i + 2],
              a3 = buf1[i + 3], a4 = buf1[i + 4];
        float s0 = fmaf(a0, RL[6], fmaf(a1, RL[4], fmaf(a2, RL[2], a3 * RL[0])));
        float s1 = fmaf(a0, RL[7], fmaf(a1, RL[5], fmaf(a2, RL[3], a3 * RL[1])));
        float s2 = fmaf(a1, RL[6], fmaf(a2, RL[4], fmaf(a3, RL[2], a4 * RL[0])));
        float s3 = fmaf(a1, RL[7], fmaf(a2, RL[5], fmaf(a3, RL[3], a4 * RL[1])));
        const float4 xv = reinterpret_cast<const float4*>(xr)[w];
        reinterpret_cast<float4*>(lowp)[w]  = make_float4(s0, s1, s2, s3);
        reinterpret_cast<float4*>(highp)[w] = make_float4(xv.x - s0, xv.y - s1,
                                                          xv.z - s2, xv.w - s3);
    }
}

extern "C" void kernel_launch(void* const* d_in, const int* in_sizes, int n_in,
                              void* d_out, int out_size, void* d_ws, size_t ws_size,
                              hipStream_t stream) {
    (void)n_in; (void)d_ws; (void)ws_size; (void)out_size;
    const float* x = (const float*)d_in[0];
    float* out = (float*)d_out;
    const int rows = in_sizes[0] / kL0;   // 2048
    hipLaunchKernelGGL(wavelet_kernel, dim3(rows), dim3(kThreads), 0, stream,
                       x, out, rows);
}